// Round 6
// baseline (129.173 us; speedup 1.0000x reference)
//
#include <hip/hip_runtime.h>

// GAT forward, O(N*HD) via sorted-prefix decomposition. B=8,N=1024,F=128,H=4,HD=32.
// score(i,j)=s_i+d_j; negative iff d_j < -s_i. Per (b,h), sort j by d_j (pos p):
//   out[i,:] = (c2*PB[k_i] + c1*SufA[k_i]) / (c2*sPB[k_i] + c1*sSF[k_i])
// PB : exclusive prefix of e^{0.2 d(p)}*h(p)   (vector, chunked: tbl + ofF)
// SufA: inclusive suffix of e^{d(p)}*h(p)      (vector, chunked: tbl + ofB)
// sPB/sSF: scalar versions, full-array scans (done in sort kernel).
// k_i = lower_bound(dsrt, -s_i); c1=e^{s_i}, c2=e^{0.2 s_i}.

constexpr int CB  = 8;
constexpr int CN  = 1024;
constexpr int CF  = 128;
constexpr int CH  = 4;
constexpr int CHD = 32;
constexpr int CBH = CB * CH;        // 32
constexpr int CROWS = CB * CN;      // 8192
constexpr int TROWS = CN + 1;       // 1025
constexpr int SStr  = CN + 1;       // sPB/sSF stride

// ---------------- K1: projection + exact s/d ----------------
// 256 blocks x 128 thr (2 waves). Block: 64 rows x 64 cols (col half = blk&1).
// lane = row; wave w -> head = 2*(blk&1)+w (32 cols). W/a reads wave-uniform ->
// scalar pipe; x via LDS b32 stride-129 (2-way banks = free). s/d = in-thread
// dot of own 32 h-values with a_src/a_dst slice (h reused, no shuffles).
__global__ __launch_bounds__(128) void proj_kernel(
    const float* __restrict__ x, const float* __restrict__ W,
    const float* __restrict__ a_src, const float* __restrict__ a_dst,
    float* __restrict__ h_ws, float* __restrict__ sarr, float* __restrict__ darr)
{
    __shared__ float xs[64 * 129];   // 33 KB
    const int tid = threadIdx.x;
    const int rt = blockIdx.x >> 1, ch = blockIdx.x & 1;

    const float4* x4 = (const float4*)x;
    #pragma unroll
    for (int m = 0; m < 16; ++m) {
        const int idx = m * 128 + tid;          // 0..2047
        const int r = idx >> 5, k4 = idx & 31;
        const float4 v = x4[(size_t)(rt * 64 + r) * 32 + k4];
        float* p = xs + r * 129 + k4 * 4;
        p[0] = v.x; p[1] = v.y; p[2] = v.z; p[3] = v.w;
    }
    __syncthreads();

    const int lane = tid & 63, wv = tid >> 6;
    const int head = __builtin_amdgcn_readfirstlane(ch * 2 + wv);
    const float* __restrict__ Wh = W + head * 32;

    float acc[32];
    #pragma unroll
    for (int c = 0; c < 32; ++c) acc[c] = 0.f;

    const float* xrow = xs + lane * 129;
    #pragma unroll 2
    for (int k = 0; k < 128; ++k) {
        const float xk = xrow[k];
        const float4* wr = (const float4*)(Wh + (size_t)k * CF);   // uniform -> s_load
        #pragma unroll
        for (int q = 0; q < 8; ++q) {
            const float4 wq = wr[q];
            acc[q*4+0] += xk * wq.x; acc[q*4+1] += xk * wq.y;
            acc[q*4+2] += xk * wq.z; acc[q*4+3] += xk * wq.w;
        }
    }

    // s/d from own h slice (a_src/a_dst uniform scalar loads)
    const float4* as4 = (const float4*)(a_src + head * 32);
    const float4* ad4 = (const float4*)(a_dst + head * 32);
    float sacc = 0.f, dacc = 0.f;
    #pragma unroll
    for (int q = 0; q < 8; ++q) {
        const float4 av = as4[q], dv = ad4[q];
        sacc += acc[q*4+0]*av.x + acc[q*4+1]*av.y + acc[q*4+2]*av.z + acc[q*4+3]*av.w;
        dacc += acc[q*4+0]*dv.x + acc[q*4+1]*dv.y + acc[q*4+2]*dv.z + acc[q*4+3]*dv.w;
    }

    const int row = rt * 64 + lane, b = row >> 10, n = row & 1023;
    const int bh = b * CH + head;
    float4* hp = (float4*)(h_ws + (size_t)(bh * CN + n) * CHD);
    #pragma unroll
    for (int q = 0; q < 8; ++q)
        hp[q] = make_float4(acc[q*4], acc[q*4+1], acc[q*4+2], acc[q*4+3]);
    sarr[bh * CN + n] = sacc;
    darr[bh * CN + n] = dacc;
}

// ---------------- K2: sort (u64 key) + coefficients + scalar scans ----------
// 32 blocks x 1024 thr. key = (monotone-fp32(d) << 32) | idx -> strict order.
// Also emits cfF=e^{0.2d}, cfB=e^{d} and FULL scalar scans sPB (excl prefix of
// cfF) / sSF (incl suffix of cfB) via wave shfl-scans + wave-total combine.
__global__ __launch_bounds__(1024) void sort_kernel(
    const float* __restrict__ darr, float* __restrict__ dsrt, int* __restrict__ perm,
    float* __restrict__ cfF, float* __restrict__ cfB,
    float* __restrict__ sPB, float* __restrict__ sSF)
{
    __shared__ unsigned long long ks[CN];   // 8 KB
    __shared__ float sc[CN];                // 4 KB
    __shared__ float wt[16];

    const int bh = blockIdx.x, tid = threadIdx.x;
    const int lane = tid & 63, wv = tid >> 6;

    const float d0 = darr[bh * CN + tid];
    const unsigned int bits = __float_as_uint(d0);
    const unsigned int msk = (unsigned int)((int)bits >> 31);
    const unsigned int k32 = bits ^ (msk | 0x80000000u);
    unsigned long long key = ((unsigned long long)k32 << 32) | (unsigned int)tid;

    for (int k = 2; k <= CN; k <<= 1) {
        for (int j = k >> 1; j > 0; j >>= 1) {
            unsigned long long pk;
            if (j >= 64) {
                ks[tid] = key;
                __syncthreads();
                pk = ks[tid ^ j];
                __syncthreads();
            } else {
                pk = __shfl_xor(key, j);
            }
            const bool up = ((tid & k) == 0), low = ((tid & j) == 0);
            if ((key > pk) == (low == up)) key = pk;
        }
    }

    // decode
    const unsigned int kk = (unsigned int)(key >> 32);
    const unsigned int ob = (kk & 0x80000000u) ? (kk ^ 0x80000000u) : ~kk;
    const float ds = __uint_as_float(ob);
    const int   pj = (int)(key & 1023u);
    dsrt[bh * CN + tid] = ds;
    perm[bh * CN + tid] = pj;
    const float cf = __expf(0.2f * ds);
    const float cb = __expf(ds);
    cfF[bh * CN + tid] = cf;
    cfB[bh * CN + tid] = cb;

    // forward scalar scan (exclusive prefix of cf)
    float v = cf;
    #pragma unroll
    for (int off = 1; off < 64; off <<= 1) {
        const float nv = __shfl_up(v, off);
        if (lane >= off) v += nv;
    }
    if (lane == 63) wt[wv] = v;
    __syncthreads();
    float basev = 0.f;
    for (int w2 = 0; w2 < wv; ++w2) basev += wt[w2];
    const float incl = v + basev;
    sPB[bh * SStr + tid] = incl - cf;
    if (tid == CN - 1) sPB[bh * SStr + CN] = incl;

    // backward scalar scan (inclusive suffix of cb): scan reversed array
    sc[(CN - 1) - tid] = cb;
    __syncthreads();                 // also guards wt reuse
    float v2 = sc[tid];
    const float own2 = v2;
    #pragma unroll
    for (int off = 1; off < 64; off <<= 1) {
        const float nv = __shfl_up(v2, off);
        if (lane >= off) v2 += nv;
    }
    if (lane == 63) wt[wv] = v2;
    __syncthreads();
    float basev2 = 0.f;
    for (int w2 = 0; w2 < wv; ++w2) basev2 += wt[w2];
    (void)own2;
    const float incl2 = v2 + basev2;
    sSF[bh * SStr + (CN - 1) - tid] = incl2;
    if (tid == 0) sSF[bh * SStr + CN] = 0.f;
}

// ---------------- K3: chunk-local vector scans ----------------
// 256 blocks x 256 thr. Block: bh = blk>>3, 4 chunks of 32 positions.
// thread = (sub, dir, dd). Fwd: exclusive prefix of cfF*h; bwd: inclusive
// suffix of cfB*h. 16-deep gather prefetch. Chunk totals to ct_g.
__global__ __launch_bounds__(256) void scan_kernel(
    const float* __restrict__ h_ws, const int* __restrict__ perm,
    const float* __restrict__ cfF, const float* __restrict__ cfB,
    float* __restrict__ tbl_g, float* __restrict__ ct_g)
{
    const int bh = blockIdx.x >> 3, g = blockIdx.x & 7;
    const int tid = threadIdx.x;
    const int sub = tid >> 6, dir = (tid >> 5) & 1, dd = tid & 31;
    const int c = g * 4 + sub;
    const int base = bh * CN + c * 32;
    const float* __restrict__ cf = dir ? cfB : cfF;
    const float* __restrict__ hb = h_ws + (size_t)bh * CN * CHD;
    float* __restrict__ tbl = tbl_g + (size_t)bh * TROWS * 64;

    float acc = 0.f;
    #pragma unroll
    for (int bt = 0; bt < 2; ++bt) {
        int jv[16]; float cv[16], hv[16];
        #pragma unroll
        for (int t = 0; t < 16; ++t) {
            const int p16 = bt * 16 + t;
            const int pos = dir ? (31 - p16) : p16;
            jv[t] = perm[base + pos];
            cv[t] = cf[base + pos];
        }
        #pragma unroll
        for (int t = 0; t < 16; ++t)
            hv[t] = hb[(size_t)jv[t] * CHD + dd];
        #pragma unroll
        for (int t = 0; t < 16; ++t) {
            const int p16 = bt * 16 + t;
            const int pos = dir ? (31 - p16) : p16;
            const int prow = c * 32 + pos;
            if (dir == 0) {
                tbl[(size_t)prow * 64 + dd] = acc;          // exclusive prefix
                acc += cv[t] * hv[t];
            } else {
                acc += cv[t] * hv[t];
                tbl[(size_t)prow * 64 + 32 + dd] = acc;     // inclusive suffix
            }
        }
    }
    ct_g[(size_t)((bh * 2 + dir) * 32 + c) * 32 + dd] = acc;
}

// ---------------- K4: chunk offsets + binary search + combine ----------------
// 32 blocks x 1024 thr (one per bh).
__global__ __launch_bounds__(1024) void out_kernel(
    const float* __restrict__ sarr, const float* __restrict__ dsrt,
    const float* __restrict__ sPB, const float* __restrict__ sSF,
    const float* __restrict__ ct_g, float* __restrict__ tbl_g,
    float* __restrict__ out)
{
    __shared__ float dsS[CN];
    __shared__ float ofF[33 * 32];
    __shared__ float ofB[33 * 32];

    const int bh = blockIdx.x, tid = threadIdx.x;
    float* __restrict__ tbl = tbl_g + (size_t)bh * TROWS * 64;

    dsS[tid] = dsrt[bh * CN + tid];
    if (tid < 64) tbl[(size_t)CN * 64 + tid] = 0.f;   // virtual row 1024 = zeros

    const int c = tid >> 5, dd = tid & 31;
    const float* ctF = ct_g + (size_t)(bh * 2 + 0) * 32 * 32;
    const float* ctB = ct_g + (size_t)(bh * 2 + 1) * 32 * 32;
    {
        float run = 0.f;
        for (int c2 = 0; c2 < c; ++c2) run += ctF[c2 * 32 + dd];
        ofF[c * 32 + dd] = run;
        if (c == 31) ofF[32 * 32 + dd] = run + ctF[31 * 32 + dd];
        float run2 = 0.f;
        for (int c2 = c + 1; c2 < 32; ++c2) run2 += ctB[c2 * 32 + dd];
        ofB[c * 32 + dd] = run2;
        if (c == 0) ofB[32 * 32 + dd] = 0.f;
    }
    __syncthreads();

    const int i = tid;
    const float s = sarr[bh * CN + i];
    const float c1 = __expf(s), c2v = __expf(0.2f * s), thr = -s;
    int lo = 0, hi = CN;
    while (lo < hi) { const int mid = (lo + hi) >> 1; if (dsS[mid] < thr) lo = mid + 1; else hi = mid; }
    const int k = lo, kc = k >> 5;                   // 0..32 (k==1024 -> 32)

    const float PBs = sPB[bh * SStr + k];
    const float SFs = sSF[bh * SStr + k];
    const float inv = 1.0f / (c2v * PBs + c1 * SFs);

    const float4* tr = (const float4*)(tbl + (size_t)k * 64);
    const int b = bh >> 2, hh = bh & 3;
    float4* o = (float4*)(out + (size_t)(b * CN + i) * CF + hh * 32);
    #pragma unroll
    for (int q = 0; q < 8; ++q) {
        const float4 pb = tr[q], sf = tr[8 + q];
        const float4 oa = *(const float4*)(&ofF[kc * 32 + q * 4]);
        const float4 ob = *(const float4*)(&ofB[kc * 32 + q * 4]);
        float4 r;
        r.x = (c2v * (pb.x + oa.x) + c1 * (sf.x + ob.x)) * inv;
        r.y = (c2v * (pb.y + oa.y) + c1 * (sf.y + ob.y)) * inv;
        r.z = (c2v * (pb.z + oa.z) + c1 * (sf.z + ob.z)) * inv;
        r.w = (c2v * (pb.w + oa.w) + c1 * (sf.w + ob.w)) * inv;
        o[q] = r;
    }
}

extern "C" void kernel_launch(void* const* d_in, const int* in_sizes, int n_in,
                              void* d_out, int out_size, void* d_ws, size_t ws_size,
                              hipStream_t stream) {
    const float* x     = (const float*)d_in[0];
    const float* W     = (const float*)d_in[1];
    const float* a_src = (const float*)d_in[2];
    const float* a_dst = (const float*)d_in[3];
    float* out = (float*)d_out;

    char* ws = (char*)d_ws;
    size_t off = 0;
    float* h_ws = (float*)(ws + off); off += (size_t)CROWS * CF * 4;            // 4 MB
    float* sarr = (float*)(ws + off); off += (size_t)CBH * CN * 4;
    float* darr = (float*)(ws + off); off += (size_t)CBH * CN * 4;
    float* dsrt = (float*)(ws + off); off += (size_t)CBH * CN * 4;
    int*   perm = (int*)  (ws + off); off += (size_t)CBH * CN * 4;
    float* cfF  = (float*)(ws + off); off += (size_t)CBH * CN * 4;
    float* cfB  = (float*)(ws + off); off += (size_t)CBH * CN * 4;
    float* sPB  = (float*)(ws + off); off += (size_t)CBH * SStr * 4;
    float* sSF  = (float*)(ws + off); off += (size_t)CBH * SStr * 4;
    float* ctg  = (float*)(ws + off); off += (size_t)CBH * 2 * 32 * 32 * 4;     // 256 KB
    float* tblg = (float*)(ws + off); off += (size_t)CBH * TROWS * 64 * 4;      // 8.4 MB
    (void)ws_size;

    proj_kernel<<<256, 128, 0, stream>>>(x, W, a_src, a_dst, h_ws, sarr, darr);
    sort_kernel<<<CBH, 1024, 0, stream>>>(darr, dsrt, perm, cfF, cfB, sPB, sSF);
    scan_kernel<<<CBH * 8, 256, 0, stream>>>(h_ws, perm, cfF, cfB, tblg, ctg);
    out_kernel<<<CBH, 1024, 0, stream>>>(sarr, dsrt, sPB, sSF, ctg, tblg, out);
}